// Round 1
// baseline (1934.427 us; speedup 1.0000x reference)
//
#include <hip/hip_runtime.h>
#include <math.h>

#define NN 1048576
#define EE 4194304
#define TPB 256
#define NBLK 2048
constexpr float BN_EPS = 1e-5f;

// ---- workspace layout (bytes) ----
#define OFF_DEG     0u
#define OFF_ROWPTR  (4u<<20)
#define OFF_ROWEND  (8u<<20)
#define OFF_SSRC    (12u<<20)          // E ints -> 16 MB
#define OFF_BSUMS   (28u<<20)          // 1024 ints
#define OFF_STATS   ((28u<<20) + 65536u)
#define OFF_HA      (32u<<20)          // N*12 floats = 48 MB
#define OFF_HB      (80u<<20)          // N*12 floats = 48 MB
#define SS 384                          // stats slot stride (floats): 24 counters * 16

// ================= CSR build =================
__global__ void k_hist(const int* __restrict__ dst, int* __restrict__ deg){
  int e = blockIdx.x*blockDim.x + threadIdx.x;
  if(e < EE) atomicAdd(&deg[dst[e]], 1);
}

__global__ void k_scan1(const int* __restrict__ deg, int* __restrict__ rowptr,
                        int* __restrict__ bsums){
  __shared__ int lds[256];
  int b = blockIdx.x, t = threadIdx.x;
  int4 d = ((const int4*)deg)[b*256 + t];
  int s0 = d.x, s1 = s0 + d.y, s2 = s1 + d.z, s3 = s2 + d.w;
  lds[t] = s3; __syncthreads();
#pragma unroll
  for(int off=1; off<256; off<<=1){
    int v = (t >= off) ? lds[t-off] : 0;
    __syncthreads();
    lds[t] += v;
    __syncthreads();
  }
  int excl = lds[t] - s3;
  int4 o; o.x = excl; o.y = excl + s0; o.z = excl + s1; o.w = excl + s2;
  ((int4*)rowptr)[b*256 + t] = o;
  if(t == 255) bsums[b] = lds[255];
}

__global__ void k_scan2(int* __restrict__ bsums){
  __shared__ int lds[256];
  int t = threadIdx.x;
  int4 d = ((int4*)bsums)[t];
  int s0 = d.x, s1 = s0 + d.y, s2 = s1 + d.z, s3 = s2 + d.w;
  lds[t] = s3; __syncthreads();
#pragma unroll
  for(int off=1; off<256; off<<=1){
    int v = (t >= off) ? lds[t-off] : 0;
    __syncthreads();
    lds[t] += v;
    __syncthreads();
  }
  int excl = lds[t] - s3;
  int4 o; o.x = excl; o.y = excl + s0; o.z = excl + s1; o.w = excl + s2;
  ((int4*)bsums)[t] = o;
}

__global__ void k_scan3(const int* __restrict__ bsums, int* __restrict__ rowptr,
                        int* __restrict__ rowend){
  int i = blockIdx.x*blockDim.x + threadIdx.x;
  int v = rowptr[i] + bsums[i >> 10];
  rowptr[i] = v;
  rowend[i] = v;   // serves as scatter cursor; after scatter == row end
}

__global__ void k_scatter(const int* __restrict__ src, const int* __restrict__ dst,
                          int* __restrict__ cursor, int* __restrict__ ssrc){
  int e = blockIdx.x*blockDim.x + threadIdx.x;
  if(e < EE){
    int p = atomicAdd(&cursor[dst[e]], 1);
    ssrc[p] = src[e];
  }
}

// ================= stats helpers =================
template<int NF>
__device__ __forceinline__ void stats_flush(float* ssum, float* ssq,
                                            float* __restrict__ stats_out){
  __shared__ float sred[2*NF];
#pragma unroll
  for(int f=0; f<NF; f++){
    float a = ssum[f], b = ssq[f];
#pragma unroll
    for(int off=1; off<64; off<<=1){
      a += __shfl_xor(a, off, 64);
      b += __shfl_xor(b, off, 64);
    }
    ssum[f] = a; ssq[f] = b;
  }
  if(threadIdx.x < 2*NF) sred[threadIdx.x] = 0.0f;
  __syncthreads();
  if((threadIdx.x & 63) == 0){
#pragma unroll
    for(int f=0; f<NF; f++){
      atomicAdd(&sred[f],      ssum[f]);
      atomicAdd(&sred[NF + f], ssq[f]);
    }
  }
  __syncthreads();
  if(threadIdx.x < 2*NF)
    atomicAdd(&stats_out[threadIdx.x * 16], sred[threadIdx.x]);  // 64B-spread counters
}

// ================= conv layer 1: x[N,3] -> h[N,12] =================
__global__ void k_layer1(const float* __restrict__ x,
                         const int* __restrict__ rowptr, const int* __restrict__ rowend,
                         const int* __restrict__ ssrc,
                         const float* __restrict__ Wl1, const float* __restrict__ Wr1,
                         const float* __restrict__ b1,
                         float* __restrict__ hout, float* __restrict__ stats_out){
  float ssum[12], ssq[12];
#pragma unroll
  for(int f=0; f<12; f++){ ssum[f]=0.f; ssq[f]=0.f; }
  int stride = gridDim.x*blockDim.x;
  for(int i = blockIdx.x*blockDim.x + threadIdx.x; i < NN; i += stride){
    int st = rowptr[i], en = rowend[i];
    float a0=0.f, a1=0.f, a2=0.f;
    for(int p=st; p<en; p++){
      int s = ssrc[p];
      a0 += x[3*s]; a1 += x[3*s+1]; a2 += x[3*s+2];
    }
    float inv = (en > st) ? 1.0f/(float)(en-st) : 0.0f;
    a0 *= inv; a1 *= inv; a2 *= inv;
    float x0 = x[3*i], x1 = x[3*i+1], x2 = x[3*i+2];
    float ov[12];
#pragma unroll
    for(int f=0; f<12; f++){
      float o = b1[f]
              + Wl1[3*f]*a0 + Wl1[3*f+1]*a1 + Wl1[3*f+2]*a2
              + Wr1[3*f]*x0 + Wr1[3*f+1]*x1 + Wr1[3*f+2]*x2;
      o = fmaxf(o, 0.0f);
      ov[f] = o; ssum[f] += o; ssq[f] += o*o;
    }
    float4* op = (float4*)(hout + 12*i);
    op[0] = make_float4(ov[0],ov[1],ov[2],ov[3]);
    op[1] = make_float4(ov[4],ov[5],ov[6],ov[7]);
    op[2] = make_float4(ov[8],ov[9],ov[10],ov[11]);
  }
  stats_flush<12>(ssum, ssq, stats_out);
}

// ========== conv layers 2..8: BN(stats_in) folded + SAGE, h[N,12] -> h[N,12] ==========
template<bool STATS>
__global__ void k_layerk(const float* __restrict__ hin,
                         const int* __restrict__ rowptr, const int* __restrict__ rowend,
                         const int* __restrict__ ssrc,
                         const float* __restrict__ Wl, const float* __restrict__ Wr,
                         const float* __restrict__ bias,
                         const float* __restrict__ bng, const float* __restrict__ bnb,
                         const float* __restrict__ stats_in,
                         float* __restrict__ hout, float* __restrict__ stats_out){
  float sc[12], sh[12];
#pragma unroll
  for(int f=0; f<12; f++){
    float m = stats_in[f*16]      * (1.0f/NN);
    float v = stats_in[(12+f)*16] * (1.0f/NN) - m*m;
    float is = rsqrtf(v + BN_EPS);
    sc[f] = bng[f]*is;
    sh[f] = bnb[f] - m*sc[f];
  }
  float ssum[12], ssq[12];
  if(STATS){
#pragma unroll
    for(int f=0; f<12; f++){ ssum[f]=0.f; ssq[f]=0.f; }
  }
  int stride = gridDim.x*blockDim.x;
  for(int i = blockIdx.x*blockDim.x + threadIdx.x; i < NN; i += stride){
    int st = rowptr[i], en = rowend[i];
    float s[12];
#pragma unroll
    for(int k=0; k<12; k++) s[k]=0.f;
    for(int p=st; p<en; p++){
      int sid = ssrc[p];
      const float4* hp = (const float4*)(hin + 12*sid);
      float4 q0 = hp[0], q1 = hp[1], q2 = hp[2];
      s[0]+=q0.x; s[1]+=q0.y; s[2]+=q0.z; s[3]+=q0.w;
      s[4]+=q1.x; s[5]+=q1.y; s[6]+=q1.z; s[7]+=q1.w;
      s[8]+=q2.x; s[9]+=q2.y; s[10]+=q2.z; s[11]+=q2.w;
    }
    float inv   = (en > st) ? 1.0f/(float)(en-st) : 0.0f;
    float zmask = (en > st) ? 1.0f : 0.0f;
    const float4* hp = (const float4*)(hin + 12*i);
    float4 r0 = hp[0], r1 = hp[1], r2 = hp[2];
    float hi[12] = {r0.x,r0.y,r0.z,r0.w, r1.x,r1.y,r1.z,r1.w, r2.x,r2.y,r2.z,r2.w};
    float aggn[12], hn[12];
#pragma unroll
    for(int k=0; k<12; k++){
      aggn[k] = (s[k]*inv*sc[k] + sh[k]) * zmask;  // mean-of-BN'd == BN-of-mean; deg=0 -> 0
      hn[k]   = hi[k]*sc[k] + sh[k];
    }
    float ov[12];
#pragma unroll
    for(int f=0; f<12; f++){
      float o = bias[f];
#pragma unroll
      for(int k=0; k<12; k++) o += Wl[12*f+k]*aggn[k];
#pragma unroll
      for(int k=0; k<12; k++) o += Wr[12*f+k]*hn[k];
      o = fmaxf(o, 0.0f);
      ov[f] = o;
      if(STATS){ ssum[f] += o; ssq[f] += o*o; }
    }
    float4* op = (float4*)(hout + 12*i);
    op[0] = make_float4(ov[0],ov[1],ov[2],ov[3]);
    op[1] = make_float4(ov[4],ov[5],ov[6],ov[7]);
    op[2] = make_float4(ov[8],ov[9],ov[10],ov[11]);
  }
  if(STATS) stats_flush<12>(ssum, ssq, stats_out);
}

// ========== head linear (+ optional preceding BN+ReLU), rows [2N,6] ==========
template<bool FIRST>
__global__ void k_head(const float* __restrict__ zin,
                       const float* __restrict__ W, const float* __restrict__ bv,
                       const float* __restrict__ g6, const float* __restrict__ b6,
                       const float* __restrict__ stats_in,
                       float* __restrict__ zout, float* __restrict__ stats_out){
  float sc[6], sh[6];
  if(!FIRST){
#pragma unroll
    for(int k=0; k<6; k++){
      float m = stats_in[k*16]     * (1.0f/(2.0f*NN));
      float v = stats_in[(6+k)*16] * (1.0f/(2.0f*NN)) - m*m;
      float is = rsqrtf(v + BN_EPS);
      sc[k] = g6[k]*is;
      sh[k] = b6[k] - m*sc[k];
    }
  }
  float ssum[6], ssq[6];
#pragma unroll
  for(int f=0; f<6; f++){ ssum[f]=0.f; ssq[f]=0.f; }
  int stride = gridDim.x*blockDim.x;
  for(int r = blockIdx.x*blockDim.x + threadIdx.x; r < 2*NN; r += stride){
    const float2* zp = (const float2*)(zin + 6*r);
    float2 p0 = zp[0], p1 = zp[1], p2 = zp[2];
    float t[6] = {p0.x, p0.y, p1.x, p1.y, p2.x, p2.y};
    if(!FIRST){
#pragma unroll
      for(int k=0; k<6; k++) t[k] = fmaxf(t[k]*sc[k] + sh[k], 0.0f);
    }
    float ov[6];
#pragma unroll
    for(int f=0; f<6; f++){
      float o = bv[f];
#pragma unroll
      for(int k=0; k<6; k++) o += W[6*f+k]*t[k];
      ov[f] = o; ssum[f] += o; ssq[f] += o*o;
    }
    float2* op = (float2*)(zout + 6*r);
    op[0] = make_float2(ov[0], ov[1]);
    op[1] = make_float2(ov[2], ov[3]);
    op[2] = make_float2(ov[4], ov[5]);
  }
  stats_flush<6>(ssum, ssq, stats_out);
}

// ========== final: BN+ReLU + Linear(6,1) + sigmoid ==========
__global__ void k_out(const float* __restrict__ zin,
                      const float* __restrict__ g6, const float* __restrict__ b6,
                      const float* __restrict__ stats_in,
                      const float* __restrict__ outW, const float* __restrict__ outb,
                      float* __restrict__ out){
  float sc[6], sh[6], w[6];
#pragma unroll
  for(int k=0; k<6; k++){
    float m = stats_in[k*16]     * (1.0f/(2.0f*NN));
    float v = stats_in[(6+k)*16] * (1.0f/(2.0f*NN)) - m*m;
    float is = rsqrtf(v + BN_EPS);
    sc[k] = g6[k]*is;
    sh[k] = b6[k] - m*sc[k];
    w[k] = outW[k];
  }
  float ob = outb[0];
  int stride = gridDim.x*blockDim.x;
  for(int r = blockIdx.x*blockDim.x + threadIdx.x; r < 2*NN; r += stride){
    const float2* zp = (const float2*)(zin + 6*r);
    float2 p0 = zp[0], p1 = zp[1], p2 = zp[2];
    float t[6] = {p0.x, p0.y, p1.x, p1.y, p2.x, p2.y};
    float o = ob;
#pragma unroll
    for(int k=0; k<6; k++) o += w[k] * fmaxf(t[k]*sc[k] + sh[k], 0.0f);
    out[r] = 1.0f / (1.0f + expf(-o));
  }
}

extern "C" void kernel_launch(void* const* d_in, const int* in_sizes, int n_in,
                              void* d_out, int out_size, void* d_ws, size_t ws_size,
                              hipStream_t stream){
  const float* x    = (const float*)d_in[0];
  const int*   ei   = (const int*)  d_in[1];
  const float* Wl1  = (const float*)d_in[2];
  const float* Wr1  = (const float*)d_in[3];
  const float* b1   = (const float*)d_in[4];
  const float* Wl   = (const float*)d_in[5];
  const float* Wr   = (const float*)d_in[6];
  const float* bb   = (const float*)d_in[7];
  const float* bng  = (const float*)d_in[8];
  const float* bnb  = (const float*)d_in[9];
  const float* linW = (const float*)d_in[10];
  const float* linb = (const float*)d_in[11];
  const float* bn6g = (const float*)d_in[12];
  const float* bn6b = (const float*)d_in[13];
  const float* outW = (const float*)d_in[14];
  const float* outb = (const float*)d_in[15];
  float* out = (float*)d_out;

  char* ws = (char*)d_ws;
  int* deg     = (int*)(ws + OFF_DEG);
  int* rowptr  = (int*)(ws + OFF_ROWPTR);
  int* rowend  = (int*)(ws + OFF_ROWEND);
  int* ssrc    = (int*)(ws + OFF_SSRC);
  int* bsums   = (int*)(ws + OFF_BSUMS);
  float* stats = (float*)(ws + OFF_STATS);
  float* hA    = (float*)(ws + OFF_HA);
  float* hB    = (float*)(ws + OFF_HB);

  const int* srcp = ei;
  const int* dstp = ei + EE;

  hipMemsetAsync(deg, 0, NN*sizeof(int), stream);
  hipMemsetAsync(stats, 0, 10*SS*sizeof(float), stream);

  k_hist   <<<EE/TPB, TPB, 0, stream>>>(dstp, deg);
  k_scan1  <<<NN/1024, 256, 0, stream>>>(deg, rowptr, bsums);
  k_scan2  <<<1, 256, 0, stream>>>(bsums);
  k_scan3  <<<NN/256, 256, 0, stream>>>(bsums, rowptr, rowend);
  k_scatter<<<EE/TPB, TPB, 0, stream>>>(srcp, dstp, rowend, ssrc);

  // conv1 (stats -> slot 0)
  k_layer1<<<NBLK, TPB, 0, stream>>>(x, rowptr, rowend, ssrc, Wl1, Wr1, b1, hA, stats);

  // conv2..conv8
  float* hi = hA; float* ho = hB;
  for(int l=0; l<7; l++){
    const float* st_in = stats + l*SS;
    float* st_out      = stats + (l+1)*SS;
    if(l < 6)
      k_layerk<true><<<NBLK, TPB, 0, stream>>>(hi, rowptr, rowend, ssrc,
        Wl + 144*l, Wr + 144*l, bb + 12*l, bng + 12*l, bnb + 12*l, st_in, ho, st_out);
    else
      k_layerk<false><<<NBLK, TPB, 0, stream>>>(hi, rowptr, rowend, ssrc,
        Wl + 144*l, Wr + 144*l, bb + 12*l, bng + 12*l, bnb + 12*l, st_in, ho, st_out);
    float* t = hi; hi = ho; ho = t;
  }
  // hi = conv8 output, viewed as [2N,6]

  // head: z1 (stats slot 7)
  k_head<true> <<<NBLK, TPB, 0, stream>>>(hi, linW, linb, bn6g, bn6b,
                                          stats + 7*SS, ho, stats + 7*SS);
  { float* t = hi; hi = ho; ho = t; }
  // z2 (slot 8)
  k_head<false><<<NBLK, TPB, 0, stream>>>(hi, linW, linb, bn6g, bn6b,
                                          stats + 7*SS, ho, stats + 8*SS);
  { float* t = hi; hi = ho; ho = t; }
  // z3 (slot 9)
  k_head<false><<<NBLK, TPB, 0, stream>>>(hi, linW, linb, bn6g, bn6b,
                                          stats + 8*SS, ho, stats + 9*SS);
  { float* t = hi; hi = ho; ho = t; }
  // final
  k_out<<<NBLK, TPB, 0, stream>>>(hi, bn6g, bn6b, stats + 9*SS, outW, outb, out);
}

// Round 2
// 1511.340 us; speedup vs baseline: 1.2799x; 1.2799x over previous
//
#include <hip/hip_runtime.h>
#include <math.h>

#define NN 1048576
#define EE 4194304
#define TPB 256
#define NBLK 2048
#define NBUCK 256
#define BNODES 4096          // nodes per bucket (NN / NBUCK)
#define CAP 20480            // bucket edge capacity (mean 16384, sigma~128)
constexpr float BN_EPS = 1e-5f;

// ---- workspace layout (bytes), total 128 MB ----
#define OFF_SSRC    0u                        // NBUCK*CAP ints = 20 MB
#define OFF_ROWPTR  20971520u                 // N ints = 4 MB
#define OFF_ROWEND  25165824u                 // N ints = 4 MB
#define OFF_CURSOR  29360128u                 // NBUCK ints
#define OFF_STATS   (29360128u + 4096u)       // 10*SS floats
#define OFF_HA      33554432u                 // N*12 floats = 48 MB
#define OFF_HB      83886080u                 // N*12 floats = 48 MB
#define OFF_EBUF    83886080u                 // NBUCK*CAP int2 = 40 MB (aliases hB; dead before conv2)
#define SS 384                                // stats slot stride (floats): 24 counters * 16

// ================= init: bucket cursors + stats zero =================
__global__ void k_init(int* __restrict__ cursor, float* __restrict__ stats){
  int t = threadIdx.x;
  cursor[t] = t * CAP;
  for(int i = t; i < 10*SS; i += 256) stats[i] = 0.0f;
}

// ============ pass B: bin edges into 256 buckets by dst>>12 ============
__global__ void k_bucket(const int* __restrict__ src, const int* __restrict__ dst,
                         int* __restrict__ cursor, int2* __restrict__ ebuf){
  __shared__ int hist[NBUCK];
  __shared__ int base[NBUCK];
  int t = threadIdx.x;
  hist[t] = 0;
  __syncthreads();
  int eb = blockIdx.x * 4096;
  int s[16], d[16], r[16];
#pragma unroll
  for(int k=0; k<16; k++){
    int e = eb + k*256 + t;
    s[k] = src[e];
    d[k] = dst[e];
    r[k] = atomicAdd(&hist[d[k] >> 12], 1);
  }
  __syncthreads();
  base[t] = atomicAdd(&cursor[t], hist[t]);
  __syncthreads();
#pragma unroll
  for(int k=0; k<16; k++){
    int b = d[k] >> 12;
    int pos = base[b] + r[k];
    if(pos < (b+1)*CAP)                 // capacity guard (never triggers for this data)
      ebuf[pos] = make_int2(s[k], d[k]);
  }
}

// ===== pass C: per-bucket counting sort -> rowptr/rowend/ssrc =====
__global__ void k_csr(const int2* __restrict__ ebuf, const int* __restrict__ cursor,
                      int* __restrict__ ssrc, int* __restrict__ rowptr,
                      int* __restrict__ rowend){
  __shared__ int hist[BNODES];
  __shared__ int part[256];
  int b = blockIdx.x, t = threadIdx.x;
  int cnt = cursor[b] - b*CAP;
  if(cnt > CAP) cnt = CAP;
  int ebase = b*CAP;
  for(int i=t; i<BNODES; i+=256) hist[i] = 0;
  __syncthreads();
  for(int i=t; i<cnt; i+=256){
    int2 e = ebuf[ebase + i];
    atomicAdd(&hist[e.y & (BNODES-1)], 1);
  }
  __syncthreads();
  int loc[16]; int sum = 0;
#pragma unroll
  for(int j=0; j<16; j++){ loc[j] = hist[t*16 + j]; sum += loc[j]; }
  part[t] = sum;
  __syncthreads();
#pragma unroll
  for(int off=1; off<256; off<<=1){
    int v = (t >= off) ? part[t-off] : 0;
    __syncthreads();
    part[t] += v;
    __syncthreads();
  }
  int run = part[t] - sum;   // exclusive prefix for this thread's 16 nodes
#pragma unroll
  for(int j=0; j<16; j++){
    int n = b*BNODES + t*16 + j;
    rowptr[n] = ebase + run;
    rowend[n] = ebase + run + loc[j];
    hist[t*16 + j] = run;
    run += loc[j];
  }
  __syncthreads();
  for(int i=t; i<cnt; i+=256){
    int2 e = ebuf[ebase + i];
    int pos = atomicAdd(&hist[e.y & (BNODES-1)], 1);
    ssrc[ebase + pos] = e.x;
  }
}

// ================= stats helpers =================
template<int NF>
__device__ __forceinline__ void stats_flush(float* ssum, float* ssq,
                                            float* __restrict__ stats_out){
  __shared__ float sred[2*NF];
#pragma unroll
  for(int f=0; f<NF; f++){
    float a = ssum[f], b = ssq[f];
#pragma unroll
    for(int off=1; off<64; off<<=1){
      a += __shfl_xor(a, off, 64);
      b += __shfl_xor(b, off, 64);
    }
    ssum[f] = a; ssq[f] = b;
  }
  if(threadIdx.x < 2*NF) sred[threadIdx.x] = 0.0f;
  __syncthreads();
  if((threadIdx.x & 63) == 0){
#pragma unroll
    for(int f=0; f<NF; f++){
      atomicAdd(&sred[f],      ssum[f]);
      atomicAdd(&sred[NF + f], ssq[f]);
    }
  }
  __syncthreads();
  if(threadIdx.x < 2*NF)
    atomicAdd(&stats_out[threadIdx.x * 16], sred[threadIdx.x]);  // 64B-spread counters
}

// ================= conv layer 1: x[N,3] -> h[N,12] =================
__global__ void k_layer1(const float* __restrict__ x,
                         const int* __restrict__ rowptr, const int* __restrict__ rowend,
                         const int* __restrict__ ssrc,
                         const float* __restrict__ Wl1, const float* __restrict__ Wr1,
                         const float* __restrict__ b1,
                         float* __restrict__ hout, float* __restrict__ stats_out){
  float ssum[12], ssq[12];
#pragma unroll
  for(int f=0; f<12; f++){ ssum[f]=0.f; ssq[f]=0.f; }
  int stride = gridDim.x*blockDim.x;
  for(int i = blockIdx.x*blockDim.x + threadIdx.x; i < NN; i += stride){
    int st = rowptr[i], en = rowend[i];
    float a0=0.f, a1=0.f, a2=0.f;
    for(int p=st; p<en; p++){
      int s = ssrc[p];
      a0 += x[3*s]; a1 += x[3*s+1]; a2 += x[3*s+2];
    }
    float inv = (en > st) ? 1.0f/(float)(en-st) : 0.0f;
    a0 *= inv; a1 *= inv; a2 *= inv;
    float x0 = x[3*i], x1 = x[3*i+1], x2 = x[3*i+2];
    float ov[12];
#pragma unroll
    for(int f=0; f<12; f++){
      float o = b1[f]
              + Wl1[3*f]*a0 + Wl1[3*f+1]*a1 + Wl1[3*f+2]*a2
              + Wr1[3*f]*x0 + Wr1[3*f+1]*x1 + Wr1[3*f+2]*x2;
      o = fmaxf(o, 0.0f);
      ov[f] = o; ssum[f] += o; ssq[f] += o*o;
    }
    float4* op = (float4*)(hout + 12*i);
    op[0] = make_float4(ov[0],ov[1],ov[2],ov[3]);
    op[1] = make_float4(ov[4],ov[5],ov[6],ov[7]);
    op[2] = make_float4(ov[8],ov[9],ov[10],ov[11]);
  }
  stats_flush<12>(ssum, ssq, stats_out);
}

// ========== conv layers 2..8: BN(stats_in) folded + SAGE, h[N,12] -> h[N,12] ==========
template<bool STATS>
__global__ void k_layerk(const float* __restrict__ hin,
                         const int* __restrict__ rowptr, const int* __restrict__ rowend,
                         const int* __restrict__ ssrc,
                         const float* __restrict__ Wl, const float* __restrict__ Wr,
                         const float* __restrict__ bias,
                         const float* __restrict__ bng, const float* __restrict__ bnb,
                         const float* __restrict__ stats_in,
                         float* __restrict__ hout, float* __restrict__ stats_out){
  float sc[12], sh[12];
#pragma unroll
  for(int f=0; f<12; f++){
    float m = stats_in[f*16]      * (1.0f/NN);
    float v = stats_in[(12+f)*16] * (1.0f/NN) - m*m;
    float is = rsqrtf(v + BN_EPS);
    sc[f] = bng[f]*is;
    sh[f] = bnb[f] - m*sc[f];
  }
  float ssum[12], ssq[12];
  if(STATS){
#pragma unroll
    for(int f=0; f<12; f++){ ssum[f]=0.f; ssq[f]=0.f; }
  }
  int stride = gridDim.x*blockDim.x;
  for(int i = blockIdx.x*blockDim.x + threadIdx.x; i < NN; i += stride){
    int st = rowptr[i], en = rowend[i];
    float s[12];
#pragma unroll
    for(int k=0; k<12; k++) s[k]=0.f;
    for(int p=st; p<en; p++){
      int sid = ssrc[p];
      const float4* hp = (const float4*)(hin + 12*sid);
      float4 q0 = hp[0], q1 = hp[1], q2 = hp[2];
      s[0]+=q0.x; s[1]+=q0.y; s[2]+=q0.z; s[3]+=q0.w;
      s[4]+=q1.x; s[5]+=q1.y; s[6]+=q1.z; s[7]+=q1.w;
      s[8]+=q2.x; s[9]+=q2.y; s[10]+=q2.z; s[11]+=q2.w;
    }
    float inv   = (en > st) ? 1.0f/(float)(en-st) : 0.0f;
    float zmask = (en > st) ? 1.0f : 0.0f;
    const float4* hp = (const float4*)(hin + 12*i);
    float4 r0 = hp[0], r1 = hp[1], r2 = hp[2];
    float hi[12] = {r0.x,r0.y,r0.z,r0.w, r1.x,r1.y,r1.z,r1.w, r2.x,r2.y,r2.z,r2.w};
    float aggn[12], hn[12];
#pragma unroll
    for(int k=0; k<12; k++){
      aggn[k] = (s[k]*inv*sc[k] + sh[k]) * zmask;  // mean-of-BN'd == BN-of-mean; deg=0 -> 0
      hn[k]   = hi[k]*sc[k] + sh[k];
    }
    float ov[12];
#pragma unroll
    for(int f=0; f<12; f++){
      float o = bias[f];
#pragma unroll
      for(int k=0; k<12; k++) o += Wl[12*f+k]*aggn[k];
#pragma unroll
      for(int k=0; k<12; k++) o += Wr[12*f+k]*hn[k];
      o = fmaxf(o, 0.0f);
      ov[f] = o;
      if(STATS){ ssum[f] += o; ssq[f] += o*o; }
    }
    float4* op = (float4*)(hout + 12*i);
    op[0] = make_float4(ov[0],ov[1],ov[2],ov[3]);
    op[1] = make_float4(ov[4],ov[5],ov[6],ov[7]);
    op[2] = make_float4(ov[8],ov[9],ov[10],ov[11]);
  }
  if(STATS) stats_flush<12>(ssum, ssq, stats_out);
}

// ========== head linear (+ optional preceding BN+ReLU), rows [2N,6] ==========
template<bool FIRST>
__global__ void k_head(const float* __restrict__ zin,
                       const float* __restrict__ W, const float* __restrict__ bv,
                       const float* __restrict__ g6, const float* __restrict__ b6,
                       const float* __restrict__ stats_in,
                       float* __restrict__ zout, float* __restrict__ stats_out){
  float sc[6], sh[6];
  if(!FIRST){
#pragma unroll
    for(int k=0; k<6; k++){
      float m = stats_in[k*16]     * (1.0f/(2.0f*NN));
      float v = stats_in[(6+k)*16] * (1.0f/(2.0f*NN)) - m*m;
      float is = rsqrtf(v + BN_EPS);
      sc[k] = g6[k]*is;
      sh[k] = b6[k] - m*sc[k];
    }
  }
  float ssum[6], ssq[6];
#pragma unroll
  for(int f=0; f<6; f++){ ssum[f]=0.f; ssq[f]=0.f; }
  int stride = gridDim.x*blockDim.x;
  for(int r = blockIdx.x*blockDim.x + threadIdx.x; r < 2*NN; r += stride){
    const float2* zp = (const float2*)(zin + 6*r);
    float2 p0 = zp[0], p1 = zp[1], p2 = zp[2];
    float t[6] = {p0.x, p0.y, p1.x, p1.y, p2.x, p2.y};
    if(!FIRST){
#pragma unroll
      for(int k=0; k<6; k++) t[k] = fmaxf(t[k]*sc[k] + sh[k], 0.0f);
    }
    float ov[6];
#pragma unroll
    for(int f=0; f<6; f++){
      float o = bv[f];
#pragma unroll
      for(int k=0; k<6; k++) o += W[6*f+k]*t[k];
      ov[f] = o; ssum[f] += o; ssq[f] += o*o;
    }
    float2* op = (float2*)(zout + 6*r);
    op[0] = make_float2(ov[0], ov[1]);
    op[1] = make_float2(ov[2], ov[3]);
    op[2] = make_float2(ov[4], ov[5]);
  }
  stats_flush<6>(ssum, ssq, stats_out);
}

// ========== final: BN+ReLU + Linear(6,1) + sigmoid ==========
__global__ void k_out(const float* __restrict__ zin,
                      const float* __restrict__ g6, const float* __restrict__ b6,
                      const float* __restrict__ stats_in,
                      const float* __restrict__ outW, const float* __restrict__ outb,
                      float* __restrict__ out){
  float sc[6], sh[6], w[6];
#pragma unroll
  for(int k=0; k<6; k++){
    float m = stats_in[k*16]     * (1.0f/(2.0f*NN));
    float v = stats_in[(6+k)*16] * (1.0f/(2.0f*NN)) - m*m;
    float is = rsqrtf(v + BN_EPS);
    sc[k] = g6[k]*is;
    sh[k] = b6[k] - m*sc[k];
    w[k] = outW[k];
  }
  float ob = outb[0];
  int stride = gridDim.x*blockDim.x;
  for(int r = blockIdx.x*blockDim.x + threadIdx.x; r < 2*NN; r += stride){
    const float2* zp = (const float2*)(zin + 6*r);
    float2 p0 = zp[0], p1 = zp[1], p2 = zp[2];
    float t[6] = {p0.x, p0.y, p1.x, p1.y, p2.x, p2.y};
    float o = ob;
#pragma unroll
    for(int k=0; k<6; k++) o += w[k] * fmaxf(t[k]*sc[k] + sh[k], 0.0f);
    out[r] = 1.0f / (1.0f + expf(-o));
  }
}

extern "C" void kernel_launch(void* const* d_in, const int* in_sizes, int n_in,
                              void* d_out, int out_size, void* d_ws, size_t ws_size,
                              hipStream_t stream){
  const float* x    = (const float*)d_in[0];
  const int*   ei   = (const int*)  d_in[1];
  const float* Wl1  = (const float*)d_in[2];
  const float* Wr1  = (const float*)d_in[3];
  const float* b1   = (const float*)d_in[4];
  const float* Wl   = (const float*)d_in[5];
  const float* Wr   = (const float*)d_in[6];
  const float* bb   = (const float*)d_in[7];
  const float* bng  = (const float*)d_in[8];
  const float* bnb  = (const float*)d_in[9];
  const float* linW = (const float*)d_in[10];
  const float* linb = (const float*)d_in[11];
  const float* bn6g = (const float*)d_in[12];
  const float* bn6b = (const float*)d_in[13];
  const float* outW = (const float*)d_in[14];
  const float* outb = (const float*)d_in[15];
  float* out = (float*)d_out;

  char* ws = (char*)d_ws;
  int*   ssrc   = (int*)  (ws + OFF_SSRC);
  int*   rowptr = (int*)  (ws + OFF_ROWPTR);
  int*   rowend = (int*)  (ws + OFF_ROWEND);
  int*   cursor = (int*)  (ws + OFF_CURSOR);
  float* stats  = (float*)(ws + OFF_STATS);
  float* hA     = (float*)(ws + OFF_HA);
  float* hB     = (float*)(ws + OFF_HB);
  int2*  ebuf   = (int2*) (ws + OFF_EBUF);   // aliases hB; consumed before conv2 writes hB

  const int* srcp = ei;
  const int* dstp = ei + EE;

  k_init  <<<1,    256, 0, stream>>>(cursor, stats);
  k_bucket<<<1024, 256, 0, stream>>>(srcp, dstp, cursor, ebuf);
  k_csr   <<<NBUCK,256, 0, stream>>>(ebuf, cursor, ssrc, rowptr, rowend);

  // conv1 (stats -> slot 0)
  k_layer1<<<NBLK, TPB, 0, stream>>>(x, rowptr, rowend, ssrc, Wl1, Wr1, b1, hA, stats);

  // conv2..conv8
  float* hi = hA; float* ho = hB;
  for(int l=0; l<7; l++){
    const float* st_in = stats + l*SS;
    float* st_out      = stats + (l+1)*SS;
    if(l < 6)
      k_layerk<true><<<NBLK, TPB, 0, stream>>>(hi, rowptr, rowend, ssrc,
        Wl + 144*l, Wr + 144*l, bb + 12*l, bng + 12*l, bnb + 12*l, st_in, ho, st_out);
    else
      k_layerk<false><<<NBLK, TPB, 0, stream>>>(hi, rowptr, rowend, ssrc,
        Wl + 144*l, Wr + 144*l, bb + 12*l, bng + 12*l, bnb + 12*l, st_in, ho, st_out);
    float* t = hi; hi = ho; ho = t;
  }
  // hi = conv8 output, viewed as [2N,6]

  // head: z1 (stats slot 7)
  k_head<true> <<<NBLK, TPB, 0, stream>>>(hi, linW, linb, bn6g, bn6b,
                                          stats + 7*SS, ho, stats + 7*SS);
  { float* t = hi; hi = ho; ho = t; }
  // z2 (slot 8)
  k_head<false><<<NBLK, TPB, 0, stream>>>(hi, linW, linb, bn6g, bn6b,
                                          stats + 7*SS, ho, stats + 8*SS);
  { float* t = hi; hi = ho; ho = t; }
  // z3 (slot 9)
  k_head<false><<<NBLK, TPB, 0, stream>>>(hi, linW, linb, bn6g, bn6b,
                                          stats + 8*SS, ho, stats + 9*SS);
  { float* t = hi; hi = ho; ho = t; }
  // final
  k_out<<<NBLK, TPB, 0, stream>>>(hi, bn6g, bn6b, stats + 9*SS, outW, outb, out);
}

// Round 3
// 1341.826 us; speedup vs baseline: 1.4416x; 1.1263x over previous
//
#include <hip/hip_runtime.h>
#include <math.h>

#define NN 1048576
#define EE 4194304
#define TPB 256
#define NBLK 2048
#define NBUCK 256
#define BNODES 4096          // nodes per bucket (NN / NBUCK)
#define CAP 20480            // bucket edge capacity (mean 16384, sigma~128)
constexpr float BN_EPS = 1e-5f;

typedef _Float16 half8  __attribute__((ext_vector_type(8)));

// ---- workspace layout (bytes), total 96 MB ----
#define OFF_SSRC    0u                        // NBUCK*CAP ints = 20 MB
#define OFF_ROWPTR  20971520u                 // N ints = 4 MB
#define OFF_ROWEND  25165824u                 // N ints = 4 MB
#define OFF_CURSOR  29360128u                 // NBUCK ints
#define OFF_STATS   (29360128u + 4096u)       // 10*SS floats
#define OFF_HA      33554432u                 // N*16 halves = 32 MB
#define OFF_HB      67108864u                 // N*16 halves = 32 MB
#define OFF_EBUF    33554432u                 // NBUCK*CAP int2 = 40 MB (aliases hA/hB; dead before conv1)
#define SS 384                                // stats slot stride (floats): 24 counters * 16

// ================= init: bucket cursors + stats zero =================
__global__ void k_init(int* __restrict__ cursor, float* __restrict__ stats){
  int t = threadIdx.x;
  cursor[t] = t * CAP;
  for(int i = t; i < 10*SS; i += 256) stats[i] = 0.0f;
}

// ============ pass B: bin edges into 256 buckets by dst>>12 ============
__global__ void k_bucket(const int* __restrict__ src, const int* __restrict__ dst,
                         int* __restrict__ cursor, int2* __restrict__ ebuf){
  __shared__ int hist[NBUCK];
  __shared__ int base[NBUCK];
  int t = threadIdx.x;
  hist[t] = 0;
  __syncthreads();
  int eb = blockIdx.x * 4096;
  int s[16], d[16], r[16];
#pragma unroll
  for(int k=0; k<16; k++){
    int e = eb + k*256 + t;
    s[k] = src[e];
    d[k] = dst[e];
    r[k] = atomicAdd(&hist[d[k] >> 12], 1);
  }
  __syncthreads();
  base[t] = atomicAdd(&cursor[t], hist[t]);
  __syncthreads();
#pragma unroll
  for(int k=0; k<16; k++){
    int b = d[k] >> 12;
    int pos = base[b] + r[k];
    if(pos < (b+1)*CAP)                 // capacity guard (never triggers for this data)
      ebuf[pos] = make_int2(s[k], d[k]);
  }
}

// ===== pass C: per-bucket counting sort -> rowptr/rowend/ssrc =====
__global__ void k_csr(const int2* __restrict__ ebuf, const int* __restrict__ cursor,
                      int* __restrict__ ssrc, int* __restrict__ rowptr,
                      int* __restrict__ rowend){
  __shared__ int hist[BNODES];
  __shared__ int part[256];
  int b = blockIdx.x, t = threadIdx.x;
  int cnt = cursor[b] - b*CAP;
  if(cnt > CAP) cnt = CAP;
  int ebase = b*CAP;
  for(int i=t; i<BNODES; i+=256) hist[i] = 0;
  __syncthreads();
  for(int i=t; i<cnt; i+=256){
    int2 e = ebuf[ebase + i];
    atomicAdd(&hist[e.y & (BNODES-1)], 1);
  }
  __syncthreads();
  int loc[16]; int sum = 0;
#pragma unroll
  for(int j=0; j<16; j++){ loc[j] = hist[t*16 + j]; sum += loc[j]; }
  part[t] = sum;
  __syncthreads();
#pragma unroll
  for(int off=1; off<256; off<<=1){
    int v = (t >= off) ? part[t-off] : 0;
    __syncthreads();
    part[t] += v;
    __syncthreads();
  }
  int run = part[t] - sum;   // exclusive prefix for this thread's 16 nodes
#pragma unroll
  for(int j=0; j<16; j++){
    int n = b*BNODES + t*16 + j;
    rowptr[n] = ebase + run;
    rowend[n] = ebase + run + loc[j];
    hist[t*16 + j] = run;
    run += loc[j];
  }
  __syncthreads();
  for(int i=t; i<cnt; i+=256){
    int2 e = ebuf[ebase + i];
    int pos = atomicAdd(&hist[e.y & (BNODES-1)], 1);
    ssrc[ebase + pos] = e.x;
  }
}

// ================= stats helpers =================
template<int NF>
__device__ __forceinline__ void stats_flush(float* ssum, float* ssq,
                                            float* __restrict__ stats_out){
  __shared__ float sred[2*NF];
#pragma unroll
  for(int f=0; f<NF; f++){
    float a = ssum[f], b = ssq[f];
#pragma unroll
    for(int off=1; off<64; off<<=1){
      a += __shfl_xor(a, off, 64);
      b += __shfl_xor(b, off, 64);
    }
    ssum[f] = a; ssq[f] = b;
  }
  if(threadIdx.x < 2*NF) sred[threadIdx.x] = 0.0f;
  __syncthreads();
  if((threadIdx.x & 63) == 0){
#pragma unroll
    for(int f=0; f<NF; f++){
      atomicAdd(&sred[f],      ssum[f]);
      atomicAdd(&sred[NF + f], ssq[f]);
    }
  }
  __syncthreads();
  if(threadIdx.x < 2*NF)
    atomicAdd(&stats_out[threadIdx.x * 16], sred[threadIdx.x]);  // 64B-spread counters
}

__device__ __forceinline__ void store_row16(_Float16* __restrict__ hout, int i,
                                            const float* ov){
  half8 o0, o1;
#pragma unroll
  for(int j=0; j<8; j++) o0[j] = (_Float16)ov[j];
#pragma unroll
  for(int j=0; j<4; j++) o1[j] = (_Float16)ov[8+j];
  o1[4]=(_Float16)0.f; o1[5]=(_Float16)0.f; o1[6]=(_Float16)0.f; o1[7]=(_Float16)0.f;
  half8* op = (half8*)(hout + 16*i);
  op[0] = o0; op[1] = o1;
}

// ================= conv layer 1: x[N,3] fp32 -> h[N,16] fp16 =================
__global__ void k_layer1(const float* __restrict__ x,
                         const int* __restrict__ rowptr, const int* __restrict__ rowend,
                         const int* __restrict__ ssrc,
                         const float* __restrict__ Wl1, const float* __restrict__ Wr1,
                         const float* __restrict__ b1,
                         _Float16* __restrict__ hout, float* __restrict__ stats_out){
  float ssum[12], ssq[12];
#pragma unroll
  for(int f=0; f<12; f++){ ssum[f]=0.f; ssq[f]=0.f; }
  int stride = gridDim.x*blockDim.x;
  for(int i = blockIdx.x*blockDim.x + threadIdx.x; i < NN; i += stride){
    int st = rowptr[i], en = rowend[i];
    float a0=0.f, a1=0.f, a2=0.f;
    int p = st;
    for(; p+4 <= en; p += 4){
      int s0=ssrc[p], s1=ssrc[p+1], s2=ssrc[p+2], s3=ssrc[p+3];
      float u0=x[3*s0], u1=x[3*s0+1], u2=x[3*s0+2];
      float v0=x[3*s1], v1=x[3*s1+1], v2=x[3*s1+2];
      float w0=x[3*s2], w1=x[3*s2+1], w2=x[3*s2+2];
      float y0=x[3*s3], y1=x[3*s3+1], y2=x[3*s3+2];
      a0 += u0+v0+w0+y0; a1 += u1+v1+w1+y1; a2 += u2+v2+w2+y2;
    }
    for(; p<en; p++){
      int s = ssrc[p];
      a0 += x[3*s]; a1 += x[3*s+1]; a2 += x[3*s+2];
    }
    float inv = (en > st) ? 1.0f/(float)(en-st) : 0.0f;
    a0 *= inv; a1 *= inv; a2 *= inv;
    float x0 = x[3*i], x1 = x[3*i+1], x2 = x[3*i+2];
    float ov[12];
#pragma unroll
    for(int f=0; f<12; f++){
      float o = b1[f]
              + Wl1[3*f]*a0 + Wl1[3*f+1]*a1 + Wl1[3*f+2]*a2
              + Wr1[3*f]*x0 + Wr1[3*f+1]*x1 + Wr1[3*f+2]*x2;
      o = fmaxf(o, 0.0f);
      ov[f] = o; ssum[f] += o; ssq[f] += o*o;
    }
    store_row16(hout, i, ov);
  }
  stats_flush<12>(ssum, ssq, stats_out);
}

// ========== conv layers 2..8: BN folded + SAGE, fp16 [N,16] -> fp16 [N,16] ==========
template<bool STATS>
__global__ void k_layerk(const _Float16* __restrict__ hin,
                         const int* __restrict__ rowptr, const int* __restrict__ rowend,
                         const int* __restrict__ ssrc,
                         const float* __restrict__ Wl, const float* __restrict__ Wr,
                         const float* __restrict__ bias,
                         const float* __restrict__ bng, const float* __restrict__ bnb,
                         const float* __restrict__ stats_in,
                         _Float16* __restrict__ hout, float* __restrict__ stats_out){
  float sc[12], sh[12];
#pragma unroll
  for(int f=0; f<12; f++){
    float m = stats_in[f*16]      * (1.0f/NN);
    float v = stats_in[(12+f)*16] * (1.0f/NN) - m*m;
    float is = rsqrtf(v + BN_EPS);
    sc[f] = bng[f]*is;
    sh[f] = bnb[f] - m*sc[f];
  }
  float ssum[12], ssq[12];
  if(STATS){
#pragma unroll
    for(int f=0; f<12; f++){ ssum[f]=0.f; ssq[f]=0.f; }
  }
  int stride = gridDim.x*blockDim.x;
  for(int i = blockIdx.x*blockDim.x + threadIdx.x; i < NN; i += stride){
    int st = rowptr[i], en = rowend[i];
    float s[12];
#pragma unroll
    for(int k=0; k<12; k++) s[k]=0.f;
    int p = st;
    for(; p+4 <= en; p += 4){
      int s0=ssrc[p], s1=ssrc[p+1], s2=ssrc[p+2], s3=ssrc[p+3];
      const half8* h0 = (const half8*)(hin + 16*s0);
      const half8* h1 = (const half8*)(hin + 16*s1);
      const half8* h2 = (const half8*)(hin + 16*s2);
      const half8* h3 = (const half8*)(hin + 16*s3);
      half8 a0=h0[0], b0=h0[1];
      half8 a1=h1[0], b1=h1[1];
      half8 a2=h2[0], b2=h2[1];
      half8 a3=h3[0], b3=h3[1];
#pragma unroll
      for(int k=0; k<8; k++)
        s[k] += (float)a0[k] + (float)a1[k] + (float)a2[k] + (float)a3[k];
#pragma unroll
      for(int k=0; k<4; k++)
        s[8+k] += (float)b0[k] + (float)b1[k] + (float)b2[k] + (float)b3[k];
    }
    for(; p<en; p++){
      int sid = ssrc[p];
      const half8* hp = (const half8*)(hin + 16*sid);
      half8 q0 = hp[0], q1 = hp[1];
#pragma unroll
      for(int k=0; k<8; k++) s[k] += (float)q0[k];
#pragma unroll
      for(int k=0; k<4; k++) s[8+k] += (float)q1[k];
    }
    float inv   = (en > st) ? 1.0f/(float)(en-st) : 0.0f;
    float zmask = (en > st) ? 1.0f : 0.0f;
    const half8* hp = (const half8*)(hin + 16*i);
    half8 r0 = hp[0], r1 = hp[1];
    float hi[12];
#pragma unroll
    for(int k=0; k<8; k++) hi[k] = (float)r0[k];
#pragma unroll
    for(int k=0; k<4; k++) hi[8+k] = (float)r1[k];
    float aggn[12], hn[12];
#pragma unroll
    for(int k=0; k<12; k++){
      aggn[k] = (s[k]*inv*sc[k] + sh[k]) * zmask;  // mean-of-BN'd == BN-of-mean; deg=0 -> 0
      hn[k]   = hi[k]*sc[k] + sh[k];
    }
    float ov[12];
#pragma unroll
    for(int f=0; f<12; f++){
      float o = bias[f];
#pragma unroll
      for(int k=0; k<12; k++) o += Wl[12*f+k]*aggn[k];
#pragma unroll
      for(int k=0; k<12; k++) o += Wr[12*f+k]*hn[k];
      o = fmaxf(o, 0.0f);
      ov[f] = o;
      if(STATS){ ssum[f] += o; ssq[f] += o*o; }
    }
    store_row16(hout, i, ov);
  }
  if(STATS) stats_flush<12>(ssum, ssq, stats_out);
}

// ========== head linear on [2N,6] stored as padded fp16 [N,16] ==========
// one thread = one padded row = two consecutive [2N,6] sub-rows
template<bool FIRST>
__global__ void k_head(const _Float16* __restrict__ zin,
                       const float* __restrict__ W, const float* __restrict__ bv,
                       const float* __restrict__ g6, const float* __restrict__ b6,
                       const float* __restrict__ stats_in,
                       _Float16* __restrict__ zout, float* __restrict__ stats_out){
  float sc[6], sh[6];
  if(!FIRST){
#pragma unroll
    for(int k=0; k<6; k++){
      float m = stats_in[k*16]     * (1.0f/(2.0f*NN));
      float v = stats_in[(6+k)*16] * (1.0f/(2.0f*NN)) - m*m;
      float is = rsqrtf(v + BN_EPS);
      sc[k] = g6[k]*is;
      sh[k] = b6[k] - m*sc[k];
    }
  }
  float ssum[6], ssq[6];
#pragma unroll
  for(int f=0; f<6; f++){ ssum[f]=0.f; ssq[f]=0.f; }
  int stride = gridDim.x*blockDim.x;
  for(int i = blockIdx.x*blockDim.x + threadIdx.x; i < NN; i += stride){
    const half8* zp = (const half8*)(zin + 16*i);
    half8 a = zp[0], b = zp[1];
    float t0[6] = {(float)a[0],(float)a[1],(float)a[2],(float)a[3],(float)a[4],(float)a[5]};
    float t1[6] = {(float)a[6],(float)a[7],(float)b[0],(float)b[1],(float)b[2],(float)b[3]};
    if(!FIRST){
#pragma unroll
      for(int k=0; k<6; k++){
        t0[k] = fmaxf(t0[k]*sc[k] + sh[k], 0.0f);
        t1[k] = fmaxf(t1[k]*sc[k] + sh[k], 0.0f);
      }
    }
    float ov[12];
#pragma unroll
    for(int f=0; f<6; f++){
      float o0 = bv[f], o1 = bv[f];
#pragma unroll
      for(int k=0; k<6; k++){ o0 += W[6*f+k]*t0[k]; o1 += W[6*f+k]*t1[k]; }
      ov[f] = o0; ov[6+f] = o1;
      ssum[f] += o0 + o1; ssq[f] += o0*o0 + o1*o1;
    }
    store_row16(zout, i, ov);
  }
  stats_flush<6>(ssum, ssq, stats_out);
}

// ========== final: BN+ReLU + Linear(6,1) + sigmoid; one thread = 2 outputs ==========
__global__ void k_out(const _Float16* __restrict__ zin,
                      const float* __restrict__ g6, const float* __restrict__ b6,
                      const float* __restrict__ stats_in,
                      const float* __restrict__ outW, const float* __restrict__ outb,
                      float* __restrict__ out){
  float sc[6], sh[6], w[6];
#pragma unroll
  for(int k=0; k<6; k++){
    float m = stats_in[k*16]     * (1.0f/(2.0f*NN));
    float v = stats_in[(6+k)*16] * (1.0f/(2.0f*NN)) - m*m;
    float is = rsqrtf(v + BN_EPS);
    sc[k] = g6[k]*is;
    sh[k] = b6[k] - m*sc[k];
    w[k] = outW[k];
  }
  float ob = outb[0];
  int stride = gridDim.x*blockDim.x;
  for(int i = blockIdx.x*blockDim.x + threadIdx.x; i < NN; i += stride){
    const half8* zp = (const half8*)(zin + 16*i);
    half8 a = zp[0], b = zp[1];
    float t0[6] = {(float)a[0],(float)a[1],(float)a[2],(float)a[3],(float)a[4],(float)a[5]};
    float t1[6] = {(float)a[6],(float)a[7],(float)b[0],(float)b[1],(float)b[2],(float)b[3]};
    float o0 = ob, o1 = ob;
#pragma unroll
    for(int k=0; k<6; k++){
      o0 += w[k] * fmaxf(t0[k]*sc[k] + sh[k], 0.0f);
      o1 += w[k] * fmaxf(t1[k]*sc[k] + sh[k], 0.0f);
    }
    float2 r;
    r.x = 1.0f / (1.0f + expf(-o0));
    r.y = 1.0f / (1.0f + expf(-o1));
    ((float2*)out)[i] = r;
  }
}

extern "C" void kernel_launch(void* const* d_in, const int* in_sizes, int n_in,
                              void* d_out, int out_size, void* d_ws, size_t ws_size,
                              hipStream_t stream){
  const float* x    = (const float*)d_in[0];
  const int*   ei   = (const int*)  d_in[1];
  const float* Wl1  = (const float*)d_in[2];
  const float* Wr1  = (const float*)d_in[3];
  const float* b1   = (const float*)d_in[4];
  const float* Wl   = (const float*)d_in[5];
  const float* Wr   = (const float*)d_in[6];
  const float* bb   = (const float*)d_in[7];
  const float* bng  = (const float*)d_in[8];
  const float* bnb  = (const float*)d_in[9];
  const float* linW = (const float*)d_in[10];
  const float* linb = (const float*)d_in[11];
  const float* bn6g = (const float*)d_in[12];
  const float* bn6b = (const float*)d_in[13];
  const float* outW = (const float*)d_in[14];
  const float* outb = (const float*)d_in[15];
  float* out = (float*)d_out;

  char* ws = (char*)d_ws;
  int*      ssrc   = (int*)     (ws + OFF_SSRC);
  int*      rowptr = (int*)     (ws + OFF_ROWPTR);
  int*      rowend = (int*)     (ws + OFF_ROWEND);
  int*      cursor = (int*)     (ws + OFF_CURSOR);
  float*    stats  = (float*)   (ws + OFF_STATS);
  _Float16* hA     = (_Float16*)(ws + OFF_HA);
  _Float16* hB     = (_Float16*)(ws + OFF_HB);
  int2*     ebuf   = (int2*)    (ws + OFF_EBUF);   // aliases hA/hB; dead after k_csr

  const int* srcp = ei;
  const int* dstp = ei + EE;

  k_init  <<<1,    256, 0, stream>>>(cursor, stats);
  k_bucket<<<1024, 256, 0, stream>>>(srcp, dstp, cursor, ebuf);
  k_csr   <<<NBUCK,256, 0, stream>>>(ebuf, cursor, ssrc, rowptr, rowend);

  // conv1 (stats -> slot 0)
  k_layer1<<<NBLK, TPB, 0, stream>>>(x, rowptr, rowend, ssrc, Wl1, Wr1, b1, hA, stats);

  // conv2..conv8
  _Float16* hi = hA; _Float16* ho = hB;
  for(int l=0; l<7; l++){
    const float* st_in = stats + l*SS;
    float* st_out      = stats + (l+1)*SS;
    if(l < 6)
      k_layerk<true><<<NBLK, TPB, 0, stream>>>(hi, rowptr, rowend, ssrc,
        Wl + 144*l, Wr + 144*l, bb + 12*l, bng + 12*l, bnb + 12*l, st_in, ho, st_out);
    else
      k_layerk<false><<<NBLK, TPB, 0, stream>>>(hi, rowptr, rowend, ssrc,
        Wl + 144*l, Wr + 144*l, bb + 12*l, bng + 12*l, bnb + 12*l, st_in, ho, st_out);
    _Float16* t = hi; hi = ho; ho = t;
  }
  // hi = conv8 output, padded fp16 rows; head views each row as two [2N,6] sub-rows

  // head: z1 (stats slot 7)
  k_head<true> <<<NBLK, TPB, 0, stream>>>(hi, linW, linb, bn6g, bn6b,
                                          stats + 7*SS, ho, stats + 7*SS);
  { _Float16* t = hi; hi = ho; ho = t; }
  // z2 (slot 8)
  k_head<false><<<NBLK, TPB, 0, stream>>>(hi, linW, linb, bn6g, bn6b,
                                          stats + 7*SS, ho, stats + 8*SS);
  { _Float16* t = hi; hi = ho; ho = t; }
  // z3 (slot 9)
  k_head<false><<<NBLK, TPB, 0, stream>>>(hi, linW, linb, bn6g, bn6b,
                                          stats + 8*SS, ho, stats + 9*SS);
  { _Float16* t = hi; hi = ho; ho = t; }
  // final
  k_out<<<NBLK, TPB, 0, stream>>>(hi, bn6g, bn6b, stats + 9*SS, outW, outb, out);
}